// Round 15
// baseline (65.582 us; speedup 1.0000x reference)
//
#include <hip/hip_runtime.h>
#include <hip/hip_fp16.h>

// Sizes (fixed):
// pc1_0: [8,2048,3] -> 16384 pts   d_in[0]
// pc1_1: [8, 512,3] ->  4096 pts   d_in[1]
// pc1_3: [8, 256,1] ->  2048 vals  d_in[2]
// pc2  : [8,2048,3] -> 16384 pts   d_in[3]
// pc3  : [8, 256,3] ->  2048 pts   d_in[4]
//
// ws layout (floats):
//   [0      ,16384) minA0 : pc1_0 -> pc2   (cd, a->b)
//   [16384  ,32768) minB0 : pc2   -> pc1_0 (cd, b->a)
//   [32768  ,36864) minA1 : pc1_1 -> pc2   (seed, a->b)
//   [36864  ,53248) minB1 : pc2   -> pc1_1 (seed, b->a)
//   [53248  ,55296) minC  : pc3[b] -> pc2[b] (confidence, full f32)
//   [55296  ,55304) acc[8]
//   [55304]         ticket

#define N_MINS 55296

typedef _Float16 half8 __attribute__((ext_vector_type(8)));
typedef float f32x16 __attribute__((ext_vector_type(16)));

__device__ __forceinline__ float blockReduceSum(float v, float* sbuf) {
#pragma unroll
  for (int off = 32; off > 0; off >>= 1) v += __shfl_down(v, off, 64);
  int lane = threadIdx.x & 63;
  int wid  = threadIdx.x >> 6;
  if (lane == 0) sbuf[wid] = v;
  __syncthreads();
  float r = 0.f;
  if (threadIdx.x == 0) r = sbuf[0] + sbuf[1] + sbuf[2] + sbuf[3];
  return r;
}

// MFMA NN-min kernel, single-barrier + 2-deep MFMA pipeline.
// Per block (256 thr, 4 waves): 128 A-points (32/wave), full 2048-point
// B-slice staged in LDS once. Entry (8 x f16 = 16B):
//   A: ( ax, ay, az, 1, 0,0,0,0)     B: (-2bx,-2by,-2bz,|b|^2, 0,0,0,0)
// One v_mfma_f32_32x32x16_f16 => 32x32 tile of (|b|^2 - 2 a.b), f32 acc.
// Entries duplicated into both k-halves => result is 2x target; folded by
// final *0.5f. C/D layout (m74/m101): col=lane&31,
// row=(reg&3)+8*(reg>>2)+4*(lane>>5).
// Pipeline: issue MFMAs for tile p+1, then min-merge tile p's results ->
// merge cluster covers MFMA result latency.
__global__ __launch_bounds__(256, 3) void k_nn_all(
    const float* __restrict__ pc10, const float* __restrict__ pc11,
    const float* __restrict__ pc2, const float* __restrict__ pc3,
    float* __restrict__ ws) {
  const int tid = threadIdx.x;
  const int blk = blockIdx.x;
  __shared__ uint4 smem4[2208];  // 35328 B

  if (blk >= 2560) {  // confidence job: per-batch NN pc3[b] -> pc2[b], f32
    float4* tile4 = (float4*)smem4;
    int j = blk - 2560;
    int b = j >> 3;
    int s = j & 7;
    int bi = b * 2048 + s * 256 + tid;
    {
      float bx = pc2[bi * 3 + 0], by = pc2[bi * 3 + 1], bz = pc2[bi * 3 + 2];
      tile4[tid] = make_float4(-2.f * bx, -2.f * by, -2.f * bz,
                               bx * bx + by * by + bz * bz);
    }
    int i = b * 256 + tid;
    float ax = pc3[i * 3 + 0], ay = pc3[i * 3 + 1], az = pc3[i * 3 + 2];
    float ra = ax * ax + ay * ay + az * az;
    __syncthreads();
    float mn = 3.0e38f;
#pragma unroll 4
    for (int t = 0; t < 256; ++t) {
      float4 q = tile4[t];
      float v = fmaf(q.x, ax, fmaf(q.y, ay, fmaf(q.z, az, q.w)));
      mn = fminf(mn, v);
    }
    atomicMin((unsigned int*)(ws + 53248 + i), __float_as_uint(fmaxf(mn + ra, 0.f)));
    return;
  }

  const float* A;
  const float* B;
  float* outMin;
  int aBase, bBase;
  if (blk < 1024) {           // job1: pc1_0 (16384) -> pc2 (16384)
    A = pc10; B = pc2; outMin = ws + 0;
    aBase = (blk >> 3) * 128; bBase = (blk & 7) * 2048;
  } else if (blk < 2048) {    // job2: pc2 (16384) -> pc1_0 (16384)
    int j = blk - 1024;
    A = pc2; B = pc10; outMin = ws + 16384;
    aBase = (j >> 3) * 128; bBase = (j & 7) * 2048;
  } else if (blk < 2304) {    // job3: pc1_1 (4096) -> pc2 (16384)
    int j = blk - 2048;
    A = pc11; B = pc2; outMin = ws + 32768;
    aBase = (j >> 3) * 128; bBase = (j & 7) * 2048;
  } else {                    // job4: pc2 (16384) -> pc1_1 (4096)
    int j = blk - 2304;
    A = pc2; B = pc11; outMin = ws + 36864;
    aBase = (j >> 1) * 128; bBase = (j & 1) * 2048;
  }

  half8* bEnt = (half8*)smem4;            // 2048 entries, 32 KB
  half8* aEnt = (half8*)(smem4 + 2048);   // 128 entries, 2 KB
  float* aRa  = (float*)(smem4 + 2176);   // 128 f32

  // A entries (threads 0-127)
  if (tid < 128) {
    int ai = aBase + tid;
    float x = A[ai * 3 + 0], y = A[ai * 3 + 1], z = A[ai * 3 + 2];
    half8 e = {};
    e[0] = (_Float16)x; e[1] = (_Float16)y; e[2] = (_Float16)z;
    e[3] = (_Float16)1.f;
    aEnt[tid] = e;
    aRa[tid] = fmaf(x, x, fmaf(y, y, z * z));
  }
  // stage full 2048-point B slice (8 entries/thread)
#pragma unroll
  for (int e = tid; e < 2048; e += 256) {
    int bi = bBase + e;
    float x = B[bi * 3 + 0], y = B[bi * 3 + 1], z = B[bi * 3 + 2];
    half8 be = {};
    be[0] = (_Float16)(-2.f * x); be[1] = (_Float16)(-2.f * y);
    be[2] = (_Float16)(-2.f * z);
    be[3] = (_Float16)(fmaf(x, x, fmaf(y, y, z * z)));
    bEnt[e] = be;
  }
  __syncthreads();

  const int l = tid & 63;
  const int wid = tid >> 6;
  const int col = l & 31;
  half8 a8 = aEnt[wid * 32 + col];

  f32x16 mn, zc;
#pragma unroll
  for (int r = 0; r < 16; ++r) { mn[r] = 3.0e38f; zc[r] = 0.f; }

  // 2-deep pipelined MFMA loop over 64 B-tiles
  f32x16 c0, c1;
  {
    half8 b0 = bEnt[col];
    half8 b1 = bEnt[32 + col];
    c0 = __builtin_amdgcn_mfma_f32_32x32x16_f16(a8, b0, zc, 0, 0, 0);
    c1 = __builtin_amdgcn_mfma_f32_32x32x16_f16(a8, b1, zc, 0, 0, 0);
  }
  for (int bt = 2; bt < 64; bt += 2) {
    half8 n0 = bEnt[bt * 32 + col];
    half8 n1 = bEnt[(bt + 1) * 32 + col];
    f32x16 d0 = __builtin_amdgcn_mfma_f32_32x32x16_f16(a8, n0, zc, 0, 0, 0);
    f32x16 d1 = __builtin_amdgcn_mfma_f32_32x32x16_f16(a8, n1, zc, 0, 0, 0);
#pragma unroll
    for (int r = 0; r < 16; ++r)
      mn[r] = fminf(fminf(mn[r], c0[r]), c1[r]);  // -> v_min3_f32
    c0 = d0;
    c1 = d1;
  }
#pragma unroll
  for (int r = 0; r < 16; ++r)
    mn[r] = fminf(fminf(mn[r], c0[r]), c1[r]);

  // min over the 32 cols (within each 32-lane half), then write 32 rows/wave
#pragma unroll
  for (int r = 0; r < 16; ++r) {
    float v = mn[r];
    v = fminf(v, __shfl_xor(v, 1));
    v = fminf(v, __shfl_xor(v, 2));
    v = fminf(v, __shfl_xor(v, 4));
    v = fminf(v, __shfl_xor(v, 8));
    v = fminf(v, __shfl_xor(v, 16));
    mn[r] = v;
  }
  if (col == 0) {
    int hi = l >> 5;
#pragma unroll
    for (int r = 0; r < 16; ++r) {
      int row = (r & 3) + 8 * (r >> 2) + 4 * hi;
      int ai = aBase + wid * 32 + row;
      float val = fmaxf(fmaf(0.5f, mn[r], aRa[wid * 32 + row]), 0.f);
      atomicMin((unsigned int*)(outMin + ai), __float_as_uint(val));
    }
  }
}

// Segmented reduce + final combine (ticket: last block writes out).
__global__ __launch_bounds__(256) void k_reduce(
    const float* __restrict__ ws, const float* __restrict__ pc13,
    const float* __restrict__ pc10, const float* __restrict__ pc2,
    float* __restrict__ acc, unsigned int* __restrict__ ticket,
    float* __restrict__ out) {
  __shared__ float sbuf[4];
  int idx = blockIdx.x * 256 + threadIdx.x;
  float v;
  int k;
  if (idx < 53248) {
    v = sqrtf(fmaxf(ws[idx], 0.f));
    k = (idx < 16384) ? 0 : (idx < 32768) ? 1 : (idx < 36864) ? 2 : 3;
  } else if (idx < 55296) {
    int i = idx - 53248;
    float score = expf(-sqrtf(fmaxf(ws[idx], 0.f)));
    float d = pc13[i] - score;
    v = d * d;
    k = 4;
  } else {
    int i = idx - 55296;
    float d = pc10[i] - pc2[i];
    v = d * d;
    k = 5;
  }
  float s = blockReduceSum(v, sbuf);
  if (threadIdx.x == 0) {
    atomicAdd(acc + k, s);
    __threadfence();
    unsigned int t = atomicAdd(ticket, 1u);
    if (t == gridDim.x - 1) {
      __threadfence();
      float cd   = (acc[0] + acc[1]) * (1.f / 16384.f);
      float seed = acc[2] * (1.f / 4096.f) + acc[3] * (1.f / 16384.f);
      float conf = acc[4] * (1.f / 2048.f);
      float p2p  = acc[5] * (1.f / 49152.f);
      out[0] = 0.5f * cd + 0.5f * seed + 0.5f * conf + p2p;
    }
  }
}

extern "C" void kernel_launch(void* const* d_in, const int* in_sizes, int n_in,
                              void* d_out, int out_size, void* d_ws, size_t ws_size,
                              hipStream_t stream) {
  const float* pc10 = (const float*)d_in[0];
  const float* pc11 = (const float*)d_in[1];
  const float* pc13 = (const float*)d_in[2];
  const float* pc2  = (const float*)d_in[3];
  const float* pc3  = (const float*)d_in[4];
  float* ws  = (float*)d_ws;
  float* acc = ws + N_MINS;
  float* out = (float*)d_out;

  // init: min arrays to ~3.39e38 (0x7F7F7F7F); acc[8]+ticket to 0
  (void)hipMemsetAsync(ws, 0x7F, N_MINS * sizeof(float), stream);
  (void)hipMemsetAsync(acc, 0, 9 * sizeof(float), stream);

  k_nn_all<<<2624, 256, 0, stream>>>(pc10, pc11, pc2, pc3, ws);

  int reduce_blocks = (N_MINS + 49152) / 256;  // 408
  k_reduce<<<reduce_blocks, 256, 0, stream>>>(ws, pc13, pc10, pc2, acc,
                                              (unsigned int*)(ws + 55304), out);
}

// Round 16
// 60.182 us; speedup vs baseline: 1.0897x; 1.0897x over previous
//
#include <hip/hip_runtime.h>
#include <hip/hip_fp16.h>

// Sizes (fixed):
// pc1_0: [8,2048,3] -> 16384 pts   d_in[0]
// pc1_1: [8, 512,3] ->  4096 pts   d_in[1]
// pc1_3: [8, 256,1] ->  2048 vals  d_in[2]
// pc2  : [8,2048,3] -> 16384 pts   d_in[3]
// pc3  : [8, 256,3] ->  2048 pts   d_in[4]
//
// ws layout (floats):
//   [0      ,16384) minA0 : pc1_0 -> pc2   (cd, a->b)
//   [16384  ,32768) minB0 : pc2   -> pc1_0 (cd, b->a)
//   [32768  ,36864) minA1 : pc1_1 -> pc2   (seed, a->b)
//   [36864  ,53248) minB1 : pc2   -> pc1_1 (seed, b->a)
//   [53248  ,55296) minC  : pc3[b] -> pc2[b] (confidence, full f32)
//   [55296  ,55304) acc[8]
//   [55304]         ticket

#define N_MINS 55296

typedef _Float16 half8 __attribute__((ext_vector_type(8)));
typedef float f32x16 __attribute__((ext_vector_type(16)));

__device__ __forceinline__ float blockReduceSum(float v, float* sbuf) {
#pragma unroll
  for (int off = 32; off > 0; off >>= 1) v += __shfl_down(v, off, 64);
  int lane = threadIdx.x & 63;
  int wid  = threadIdx.x >> 6;
  if (lane == 0) sbuf[wid] = v;
  __syncthreads();
  float r = 0.f;
  if (threadIdx.x == 0) r = sbuf[0] + sbuf[1] + sbuf[2] + sbuf[3];
  return r;
}

// MFMA NN-min kernel, 2 A-fragments per wave (halves LDS reads per pair).
// Per block (256 thr, 4 waves): 256 A-points (64/wave), B-slice 2048 in 2
// LDS chunks of 1024. Entry (8 x f16 = 16B):
//   A: ( ax, ay, az, 1, 0,0,0,0)     B: (-2bx,-2by,-2bz,|b|^2, 0,0,0,0)
// One v_mfma_f32_32x32x16_f16 => 32x32 tile of (|b|^2 - 2 a.b), f32 acc.
// Entries duplicated into both k-halves => result is 2x target; folded by
// final *0.5f. C/D layout (verified R13-R15, absmax 0): col=lane&31,
// row=(reg&3)+8*(reg>>2)+4*(lane>>5).
// Inner iter (2 B-tiles): 2 ds_read_b128, 4 MFMAs, 32 v_min3_f32.
__global__ __launch_bounds__(256, 3) void k_nn_all(
    const float* __restrict__ pc10, const float* __restrict__ pc11,
    const float* __restrict__ pc2, const float* __restrict__ pc3,
    float* __restrict__ ws) {
  const int tid = threadIdx.x;
  const int blk = blockIdx.x;
  __shared__ uint4 smem4[1344];  // 21504 B

  if (blk >= 1280) {  // confidence job: per-batch NN pc3[b] -> pc2[b], f32
    float4* tile4 = (float4*)smem4;
    int j = blk - 1280;
    int b = j >> 3;
    int s = j & 7;
    int bi = b * 2048 + s * 256 + tid;
    {
      float bx = pc2[bi * 3 + 0], by = pc2[bi * 3 + 1], bz = pc2[bi * 3 + 2];
      tile4[tid] = make_float4(-2.f * bx, -2.f * by, -2.f * bz,
                               bx * bx + by * by + bz * bz);
    }
    int i = b * 256 + tid;
    float ax = pc3[i * 3 + 0], ay = pc3[i * 3 + 1], az = pc3[i * 3 + 2];
    float ra = ax * ax + ay * ay + az * az;
    __syncthreads();
    float mn = 3.0e38f;
#pragma unroll 4
    for (int t = 0; t < 256; ++t) {
      float4 q = tile4[t];
      float v = fmaf(q.x, ax, fmaf(q.y, ay, fmaf(q.z, az, q.w)));
      mn = fminf(mn, v);
    }
    atomicMin((unsigned int*)(ws + 53248 + i), __float_as_uint(fmaxf(mn + ra, 0.f)));
    return;
  }

  const float* A;
  const float* B;
  float* outMin;
  int aBase, bBase;
  if (blk < 512) {            // job1: pc1_0 (16384) -> pc2 (16384)
    A = pc10; B = pc2; outMin = ws + 0;
    aBase = (blk >> 3) * 256; bBase = (blk & 7) * 2048;
  } else if (blk < 1024) {    // job2: pc2 (16384) -> pc1_0 (16384)
    int j = blk - 512;
    A = pc2; B = pc10; outMin = ws + 16384;
    aBase = (j >> 3) * 256; bBase = (j & 7) * 2048;
  } else if (blk < 1152) {    // job3: pc1_1 (4096) -> pc2 (16384)
    int j = blk - 1024;
    A = pc11; B = pc2; outMin = ws + 32768;
    aBase = (j >> 3) * 256; bBase = (j & 7) * 2048;
  } else {                    // job4: pc2 (16384) -> pc1_1 (4096)
    int j = blk - 1152;
    A = pc2; B = pc11; outMin = ws + 36864;
    aBase = (j >> 1) * 256; bBase = (j & 1) * 2048;
  }

  half8* bEnt = (half8*)smem4;            // 1024 entries, 16 KB
  half8* aEnt = (half8*)(smem4 + 1024);   // 256 entries, 4 KB
  float* aRa  = (float*)(smem4 + 1280);   // 256 f32, 1 KB

  // A entries (one per thread)
  {
    int ai = aBase + tid;
    float x = A[ai * 3 + 0], y = A[ai * 3 + 1], z = A[ai * 3 + 2];
    half8 e = {};
    e[0] = (_Float16)x; e[1] = (_Float16)y; e[2] = (_Float16)z;
    e[3] = (_Float16)1.f;
    aEnt[tid] = e;
    aRa[tid] = fmaf(x, x, fmaf(y, y, z * z));
  }
  // stage B chunk 0
#pragma unroll
  for (int e = tid; e < 1024; e += 256) {
    int bi = bBase + e;
    float x = B[bi * 3 + 0], y = B[bi * 3 + 1], z = B[bi * 3 + 2];
    half8 be = {};
    be[0] = (_Float16)(-2.f * x); be[1] = (_Float16)(-2.f * y);
    be[2] = (_Float16)(-2.f * z);
    be[3] = (_Float16)(fmaf(x, x, fmaf(y, y, z * z)));
    bEnt[e] = be;
  }
  __syncthreads();

  const int l = tid & 63;
  const int wid = tid >> 6;
  const int col = l & 31;
  half8 a80 = aEnt[wid * 64 + col];
  half8 a81 = aEnt[wid * 64 + 32 + col];

  f32x16 mn0, mn1, zc;
#pragma unroll
  for (int r = 0; r < 16; ++r) { mn0[r] = 3.0e38f; mn1[r] = 3.0e38f; zc[r] = 0.f; }

  for (int c = 0; c < 2; ++c) {
    if (c) {
      __syncthreads();
#pragma unroll
      for (int e = tid; e < 1024; e += 256) {
        int bi = bBase + 1024 + e;
        float x = B[bi * 3 + 0], y = B[bi * 3 + 1], z = B[bi * 3 + 2];
        half8 be = {};
        be[0] = (_Float16)(-2.f * x); be[1] = (_Float16)(-2.f * y);
        be[2] = (_Float16)(-2.f * z);
        be[3] = (_Float16)(fmaf(x, x, fmaf(y, y, z * z)));
        bEnt[e] = be;
      }
      __syncthreads();
    }
    for (int bt = 0; bt < 32; bt += 2) {
      half8 b0 = bEnt[bt * 32 + col];
      half8 b1 = bEnt[(bt + 1) * 32 + col];
      f32x16 c00 = __builtin_amdgcn_mfma_f32_32x32x16_f16(a80, b0, zc, 0, 0, 0);
      f32x16 c10 = __builtin_amdgcn_mfma_f32_32x32x16_f16(a81, b0, zc, 0, 0, 0);
      f32x16 c01 = __builtin_amdgcn_mfma_f32_32x32x16_f16(a80, b1, zc, 0, 0, 0);
      f32x16 c11 = __builtin_amdgcn_mfma_f32_32x32x16_f16(a81, b1, zc, 0, 0, 0);
#pragma unroll
      for (int r = 0; r < 16; ++r) {
        mn0[r] = fminf(fminf(mn0[r], c00[r]), c01[r]);  // -> v_min3_f32
        mn1[r] = fminf(fminf(mn1[r], c10[r]), c11[r]);
      }
    }
  }

  // min over the 32 cols (within each 32-lane half), then write 64 rows/wave
#pragma unroll
  for (int r = 0; r < 16; ++r) {
    float v0 = mn0[r], v1 = mn1[r];
    v0 = fminf(v0, __shfl_xor(v0, 1));
    v1 = fminf(v1, __shfl_xor(v1, 1));
    v0 = fminf(v0, __shfl_xor(v0, 2));
    v1 = fminf(v1, __shfl_xor(v1, 2));
    v0 = fminf(v0, __shfl_xor(v0, 4));
    v1 = fminf(v1, __shfl_xor(v1, 4));
    v0 = fminf(v0, __shfl_xor(v0, 8));
    v1 = fminf(v1, __shfl_xor(v1, 8));
    v0 = fminf(v0, __shfl_xor(v0, 16));
    v1 = fminf(v1, __shfl_xor(v1, 16));
    mn0[r] = v0;
    mn1[r] = v1;
  }
  if (col == 0) {
    int hi = l >> 5;
#pragma unroll
    for (int r = 0; r < 16; ++r) {
      int row = (r & 3) + 8 * (r >> 2) + 4 * hi;
      int a0 = aBase + wid * 64 + row;
      int a1 = a0 + 32;
      atomicMin((unsigned int*)(outMin + a0),
                __float_as_uint(fmaxf(fmaf(0.5f, mn0[r], aRa[wid * 64 + row]), 0.f)));
      atomicMin((unsigned int*)(outMin + a1),
                __float_as_uint(fmaxf(fmaf(0.5f, mn1[r], aRa[wid * 64 + 32 + row]), 0.f)));
    }
  }
}

// Segmented reduce + final combine (ticket: last block writes out).
__global__ __launch_bounds__(256) void k_reduce(
    const float* __restrict__ ws, const float* __restrict__ pc13,
    const float* __restrict__ pc10, const float* __restrict__ pc2,
    float* __restrict__ acc, unsigned int* __restrict__ ticket,
    float* __restrict__ out) {
  __shared__ float sbuf[4];
  int idx = blockIdx.x * 256 + threadIdx.x;
  float v;
  int k;
  if (idx < 53248) {
    v = sqrtf(fmaxf(ws[idx], 0.f));
    k = (idx < 16384) ? 0 : (idx < 32768) ? 1 : (idx < 36864) ? 2 : 3;
  } else if (idx < 55296) {
    int i = idx - 53248;
    float score = expf(-sqrtf(fmaxf(ws[idx], 0.f)));
    float d = pc13[i] - score;
    v = d * d;
    k = 4;
  } else {
    int i = idx - 55296;
    float d = pc10[i] - pc2[i];
    v = d * d;
    k = 5;
  }
  float s = blockReduceSum(v, sbuf);
  if (threadIdx.x == 0) {
    atomicAdd(acc + k, s);
    __threadfence();
    unsigned int t = atomicAdd(ticket, 1u);
    if (t == gridDim.x - 1) {
      __threadfence();
      float cd   = (acc[0] + acc[1]) * (1.f / 16384.f);
      float seed = acc[2] * (1.f / 4096.f) + acc[3] * (1.f / 16384.f);
      float conf = acc[4] * (1.f / 2048.f);
      float p2p  = acc[5] * (1.f / 49152.f);
      out[0] = 0.5f * cd + 0.5f * seed + 0.5f * conf + p2p;
    }
  }
}

extern "C" void kernel_launch(void* const* d_in, const int* in_sizes, int n_in,
                              void* d_out, int out_size, void* d_ws, size_t ws_size,
                              hipStream_t stream) {
  const float* pc10 = (const float*)d_in[0];
  const float* pc11 = (const float*)d_in[1];
  const float* pc13 = (const float*)d_in[2];
  const float* pc2  = (const float*)d_in[3];
  const float* pc3  = (const float*)d_in[4];
  float* ws  = (float*)d_ws;
  float* acc = ws + N_MINS;
  float* out = (float*)d_out;

  // init: min arrays to ~3.39e38 (0x7F7F7F7F); acc[8]+ticket to 0
  (void)hipMemsetAsync(ws, 0x7F, N_MINS * sizeof(float), stream);
  (void)hipMemsetAsync(acc, 0, 9 * sizeof(float), stream);

  k_nn_all<<<1344, 256, 0, stream>>>(pc10, pc11, pc2, pc3, ws);

  int reduce_blocks = (N_MINS + 49152) / 256;  // 408
  k_reduce<<<reduce_blocks, 256, 0, stream>>>(ws, pc13, pc10, pc2, acc,
                                              (unsigned int*)(ws + 55304), out);
}

// Round 18
// 58.005 us; speedup vs baseline: 1.1306x; 1.0375x over previous
//
#include <hip/hip_runtime.h>
#include <hip/hip_fp16.h>

// Sizes (fixed):
// pc1_0: [8,2048,3] -> 16384 pts   d_in[0]
// pc1_1: [8, 512,3] ->  4096 pts   d_in[1]
// pc1_3: [8, 256,1] ->  2048 vals  d_in[2]
// pc2  : [8,2048,3] -> 16384 pts   d_in[3]
// pc3  : [8, 256,3] ->  2048 pts   d_in[4]
//
// ws layout (floats):
//   [0      ,16384) minA0 : pc1_0 -> pc2   (cd, a->b)
//   [16384  ,32768) minB0 : pc2   -> pc1_0 (cd, b->a)
//   [32768  ,36864) minA1 : pc1_1 -> pc2   (seed, a->b)
//   [36864  ,53248) minB1 : pc2   -> pc1_1 (seed, b->a)
//   [53248  ,55296) minC  : pc3[b] -> pc2[b] (confidence, full f32)
//   [55296  ,55304) acc[8]
//   [55304]         ticket

#define N_MINS 55296

typedef _Float16 half8 __attribute__((ext_vector_type(8)));
typedef float f32x16 __attribute__((ext_vector_type(16)));

__device__ __forceinline__ float blockReduceSum(float v, float* sbuf) {
#pragma unroll
  for (int off = 32; off > 0; off >>= 1) v += __shfl_down(v, off, 64);
  int lane = threadIdx.x & 63;
  int wid  = threadIdx.x >> 6;
  if (lane == 0) sbuf[wid] = v;
  __syncthreads();
  float r = 0.f;
  if (threadIdx.x == 0) r = sbuf[0] + sbuf[1] + sbuf[2] + sbuf[3];
  return r;
}

// MFMA NN-min kernel, 2 A-frags/wave + register-level software pipeline.
// Per block (256 thr, 4 waves): 256 A-points (64/wave), B-slice 2048 in 2
// LDS chunks of 1024. Entry (8 x f16 = 16B):
//   A: ( ax, ay, az, 1, 0,0,0,0)     B: (-2bx,-2by,-2bz,|b|^2, 0,0,0,0)
// One v_mfma_f32_32x32x16_f16 => 32x32 tile of (|b|^2 - 2 a.b), f32 acc.
// Entries duplicated into both k-halves => result is 2x target; folded by
// final *0.5f. C/D layout (verified R13-R16, absmax 0): col=lane&31,
// row=(reg&3)+8*(reg>>2)+4*(lane>>5).
// Pipeline: a80's results (c00,c01) carried across iterations and merged
// with zero wait after the next iteration's MFMAs are issued; a81's results
// merged late in the same iteration (partially aged). Live regs ~150 < 170.
__global__ __launch_bounds__(256, 3) void k_nn_all(
    const float* __restrict__ pc10, const float* __restrict__ pc11,
    const float* __restrict__ pc2, const float* __restrict__ pc3,
    float* __restrict__ ws) {
  const int tid = threadIdx.x;
  const int blk = blockIdx.x;
  __shared__ uint4 smem4[1344];  // 21504 B

  if (blk >= 1280) {  // confidence job: per-batch NN pc3[b] -> pc2[b], f32
    float4* tile4 = (float4*)smem4;
    int j = blk - 1280;
    if (j == 0 && tid < 9) ws[55296 + tid] = 0.f;  // zero acc[8] + ticket
    int b = j >> 3;
    int s = j & 7;
    int bi = b * 2048 + s * 256 + tid;
    {
      float bx = pc2[bi * 3 + 0], by = pc2[bi * 3 + 1], bz = pc2[bi * 3 + 2];
      tile4[tid] = make_float4(-2.f * bx, -2.f * by, -2.f * bz,
                               bx * bx + by * by + bz * bz);
    }
    int i = b * 256 + tid;
    float ax = pc3[i * 3 + 0], ay = pc3[i * 3 + 1], az = pc3[i * 3 + 2];
    float ra = ax * ax + ay * ay + az * az;
    __syncthreads();
    float mn = 3.0e38f;
#pragma unroll 4
    for (int t = 0; t < 256; ++t) {
      float4 q = tile4[t];
      float v = fmaf(q.x, ax, fmaf(q.y, ay, fmaf(q.z, az, q.w)));
      mn = fminf(mn, v);
    }
    atomicMin((unsigned int*)(ws + 53248 + i), __float_as_uint(fmaxf(mn + ra, 0.f)));
    return;
  }

  const float* A;
  const float* B;
  float* outMin;
  int aBase, bBase;
  if (blk < 512) {            // job1: pc1_0 (16384) -> pc2 (16384)
    A = pc10; B = pc2; outMin = ws + 0;
    aBase = (blk >> 3) * 256; bBase = (blk & 7) * 2048;
  } else if (blk < 1024) {    // job2: pc2 (16384) -> pc1_0 (16384)
    int j = blk - 512;
    A = pc2; B = pc10; outMin = ws + 16384;
    aBase = (j >> 3) * 256; bBase = (j & 7) * 2048;
  } else if (blk < 1152) {    // job3: pc1_1 (4096) -> pc2 (16384)
    int j = blk - 1024;
    A = pc11; B = pc2; outMin = ws + 32768;
    aBase = (j >> 3) * 256; bBase = (j & 7) * 2048;
  } else {                    // job4: pc2 (16384) -> pc1_1 (4096)
    int j = blk - 1152;
    A = pc2; B = pc11; outMin = ws + 36864;
    aBase = (j >> 1) * 256; bBase = (j & 1) * 2048;
  }

  half8* bEnt = (half8*)smem4;            // 1024 entries, 16 KB
  half8* aEnt = (half8*)(smem4 + 1024);   // 256 entries, 4 KB
  float* aRa  = (float*)(smem4 + 1280);   // 256 f32, 1 KB

  // A entries (one per thread)
  {
    int ai = aBase + tid;
    float x = A[ai * 3 + 0], y = A[ai * 3 + 1], z = A[ai * 3 + 2];
    half8 e = {};
    e[0] = (_Float16)x; e[1] = (_Float16)y; e[2] = (_Float16)z;
    e[3] = (_Float16)1.f;
    aEnt[tid] = e;
    aRa[tid] = fmaf(x, x, fmaf(y, y, z * z));
  }
  // stage B chunk 0
#pragma unroll
  for (int e = tid; e < 1024; e += 256) {
    int bi = bBase + e;
    float x = B[bi * 3 + 0], y = B[bi * 3 + 1], z = B[bi * 3 + 2];
    half8 be = {};
    be[0] = (_Float16)(-2.f * x); be[1] = (_Float16)(-2.f * y);
    be[2] = (_Float16)(-2.f * z);
    be[3] = (_Float16)(fmaf(x, x, fmaf(y, y, z * z)));
    bEnt[e] = be;
  }
  __syncthreads();

  const int l = tid & 63;
  const int wid = tid >> 6;
  const int col = l & 31;
  half8 a80 = aEnt[wid * 64 + col];
  half8 a81 = aEnt[wid * 64 + 32 + col];

  f32x16 mn0, mn1, zc;
#pragma unroll
  for (int r = 0; r < 16; ++r) { mn0[r] = 3.0e38f; mn1[r] = 3.0e38f; zc[r] = 0.f; }

  f32x16 c00, c01;  // pipelined a80 results
  for (int c = 0; c < 2; ++c) {
    if (c) {
      __syncthreads();
#pragma unroll
      for (int e = tid; e < 1024; e += 256) {
        int bi = bBase + 1024 + e;
        float x = B[bi * 3 + 0], y = B[bi * 3 + 1], z = B[bi * 3 + 2];
        half8 be = {};
        be[0] = (_Float16)(-2.f * x); be[1] = (_Float16)(-2.f * y);
        be[2] = (_Float16)(-2.f * z);
        be[3] = (_Float16)(fmaf(x, x, fmaf(y, y, z * z)));
        bEnt[e] = be;
      }
      __syncthreads();
    }
    // prologue: tiles 0,1
    {
      half8 b0 = bEnt[col];
      half8 b1 = bEnt[32 + col];
      c00 = __builtin_amdgcn_mfma_f32_32x32x16_f16(a80, b0, zc, 0, 0, 0);
      c01 = __builtin_amdgcn_mfma_f32_32x32x16_f16(a80, b1, zc, 0, 0, 0);
      f32x16 c10 = __builtin_amdgcn_mfma_f32_32x32x16_f16(a81, b0, zc, 0, 0, 0);
      f32x16 c11 = __builtin_amdgcn_mfma_f32_32x32x16_f16(a81, b1, zc, 0, 0, 0);
#pragma unroll
      for (int r = 0; r < 16; ++r)
        mn1[r] = fminf(fminf(mn1[r], c10[r]), c11[r]);
    }
    for (int bt = 2; bt < 32; bt += 2) {
      half8 n0 = bEnt[bt * 32 + col];
      half8 n1 = bEnt[(bt + 1) * 32 + col];
      f32x16 d00 = __builtin_amdgcn_mfma_f32_32x32x16_f16(a80, n0, zc, 0, 0, 0);
      f32x16 d01 = __builtin_amdgcn_mfma_f32_32x32x16_f16(a80, n1, zc, 0, 0, 0);
      f32x16 d10 = __builtin_amdgcn_mfma_f32_32x32x16_f16(a81, n0, zc, 0, 0, 0);
      f32x16 d11 = __builtin_amdgcn_mfma_f32_32x32x16_f16(a81, n1, zc, 0, 0, 0);
      // merge previous a80 results (aged a full iteration: zero wait)
#pragma unroll
      for (int r = 0; r < 16; ++r)
        mn0[r] = fminf(fminf(mn0[r], c00[r]), c01[r]);  // -> v_min3_f32
      // merge this iteration's a81 results (aged by the 16 min3 above)
#pragma unroll
      for (int r = 0; r < 16; ++r)
        mn1[r] = fminf(fminf(mn1[r], d10[r]), d11[r]);
      c00 = d00;
      c01 = d01;
    }
    // epilogue merge of the last a80 pair (fills the staging barrier wait)
#pragma unroll
    for (int r = 0; r < 16; ++r)
      mn0[r] = fminf(fminf(mn0[r], c00[r]), c01[r]);
  }

  // min over the 32 cols (within each 32-lane half), then write 64 rows/wave
#pragma unroll
  for (int r = 0; r < 16; ++r) {
    float v0 = mn0[r], v1 = mn1[r];
    v0 = fminf(v0, __shfl_xor(v0, 1));
    v1 = fminf(v1, __shfl_xor(v1, 1));
    v0 = fminf(v0, __shfl_xor(v0, 2));
    v1 = fminf(v1, __shfl_xor(v1, 2));
    v0 = fminf(v0, __shfl_xor(v0, 4));
    v1 = fminf(v1, __shfl_xor(v1, 4));
    v0 = fminf(v0, __shfl_xor(v0, 8));
    v1 = fminf(v1, __shfl_xor(v1, 8));
    v0 = fminf(v0, __shfl_xor(v0, 16));
    v1 = fminf(v1, __shfl_xor(v1, 16));
    mn0[r] = v0;
    mn1[r] = v1;
  }
  if (col == 0) {
    int hi = l >> 5;
#pragma unroll
    for (int r = 0; r < 16; ++r) {
      int row = (r & 3) + 8 * (r >> 2) + 4 * hi;
      int a0 = aBase + wid * 64 + row;
      int a1 = a0 + 32;
      atomicMin((unsigned int*)(outMin + a0),
                __float_as_uint(fmaxf(fmaf(0.5f, mn0[r], aRa[wid * 64 + row]), 0.f)));
      atomicMin((unsigned int*)(outMin + a1),
                __float_as_uint(fmaxf(fmaf(0.5f, mn1[r], aRa[wid * 64 + 32 + row]), 0.f)));
    }
  }
}

// Segmented reduce + final combine (ticket: last block writes out).
__global__ __launch_bounds__(256) void k_reduce(
    const float* __restrict__ ws, const float* __restrict__ pc13,
    const float* __restrict__ pc10, const float* __restrict__ pc2,
    float* __restrict__ acc, unsigned int* __restrict__ ticket,
    float* __restrict__ out) {
  __shared__ float sbuf[4];
  int idx = blockIdx.x * 256 + threadIdx.x;
  float v;
  int k;
  if (idx < 53248) {
    v = sqrtf(fmaxf(ws[idx], 0.f));
    k = (idx < 16384) ? 0 : (idx < 32768) ? 1 : (idx < 36864) ? 2 : 3;
  } else if (idx < 55296) {
    int i = idx - 53248;
    float score = expf(-sqrtf(fmaxf(ws[idx], 0.f)));
    float d = pc13[i] - score;
    v = d * d;
    k = 4;
  } else {
    int i = idx - 55296;
    float d = pc10[i] - pc2[i];
    v = d * d;
    k = 5;
  }
  float s = blockReduceSum(v, sbuf);
  if (threadIdx.x == 0) {
    atomicAdd(acc + k, s);
    __threadfence();
    unsigned int t = atomicAdd(ticket, 1u);
    if (t == gridDim.x - 1) {
      __threadfence();
      float cd   = (acc[0] + acc[1]) * (1.f / 16384.f);
      float seed = acc[2] * (1.f / 4096.f) + acc[3] * (1.f / 16384.f);
      float conf = acc[4] * (1.f / 2048.f);
      float p2p  = acc[5] * (1.f / 49152.f);
      out[0] = 0.5f * cd + 0.5f * seed + 0.5f * conf + p2p;
    }
  }
}

extern "C" void kernel_launch(void* const* d_in, const int* in_sizes, int n_in,
                              void* d_out, int out_size, void* d_ws, size_t ws_size,
                              hipStream_t stream) {
  const float* pc10 = (const float*)d_in[0];
  const float* pc11 = (const float*)d_in[1];
  const float* pc13 = (const float*)d_in[2];
  const float* pc2  = (const float*)d_in[3];
  const float* pc3  = (const float*)d_in[4];
  float* ws  = (float*)d_ws;
  float* acc = ws + N_MINS;
  float* out = (float*)d_out;

  // init: min arrays to ~3.39e38 (0x7F7F7F7F); acc/ticket zeroed in k_nn_all
  (void)hipMemsetAsync(ws, 0x7F, N_MINS * sizeof(float), stream);

  k_nn_all<<<1344, 256, 0, stream>>>(pc10, pc11, pc2, pc3, ws);

  int reduce_blocks = (N_MINS + 49152) / 256;  // 408
  k_reduce<<<reduce_blocks, 256, 0, stream>>>(ws, pc13, pc10, pc2, acc,
                                              (unsigned int*)(ws + 55304), out);
}